// Round 4
// baseline (546.290 us; speedup 1.0000x reference)
//
#include <hip/hip_runtime.h>
#include <math.h>

#define B_ 2
#define C_ 36
#define H_ 512
#define W_ 512
#define K_ 9
#define HW_ (H_ * W_)
#define ROWF4 (W_ * C_ / 4)  // float4 pitch of one image row in featT = 4608

// ---------------------------------------------------------------------------
// Transpose features [B,C,H,W] -> [B,H,W,C], v2.
// One block = one (b,h,256-w strip).  Reads: per channel a 1 KB contiguous
// run (vs 256 B in v1) so each of the 36 1MB-strided streams is visited with
// 4x larger chunks -> better DRAM efficiency.  LDS tile [256][37] is
// conflict-free on the scalar write side (stride 37 mod 32 = 5) and ~2-way on
// the float4 read side.  Writes are fully-coalesced float4 runs.
// ---------------------------------------------------------------------------
__global__ __launch_bounds__(256) void transpose_kernel2(const float* __restrict__ in,
                                                         float* __restrict__ out) {
  __shared__ float tile[256][37];  // 37.9 KB
  int blk = blockIdx.x;            // (b*H + h)*2 + strip
  int strip = blk & 1;
  int h = (blk >> 1) & (H_ - 1);
  int b = blk >> 10;
  int w0 = strip << 8;
  int tid = threadIdx.x;
  const float* src = in + (size_t)b * C_ * HW_ + (size_t)h * W_ + w0;
#pragma unroll
  for (int c = 0; c < C_; ++c) {
    tile[tid][c] = src[(size_t)c * HW_ + tid];
  }
  __syncthreads();
  float4* dst = reinterpret_cast<float4*>(out + (((size_t)b * H_ + h) * W_ + w0) * C_);
#pragma unroll
  for (int it = 0; it < 9; ++it) {
    int idx = it * 256 + tid;  // float4 index 0..2303
    int px = idx / 9;
    int qq = idx - 9 * px;
    dst[idx] = make_float4(tile[px][4 * qq + 0], tile[px][4 * qq + 1],
                           tile[px][4 * qq + 2], tile[px][4 * qq + 3]);
  }
}

// ---------------------------------------------------------------------------
// v7: v4's cooperative-gather structure + K split across 3 waves per WG.
// Diagnosis from v4/v5/v6: eval is bound by L1 line-transaction throughput on
// the gathers (~38 cyc per 9-lane-coalesced wave-VMEM, ~52M lines total ->
// ~85us floor), and v4 sat at only 6.5 waves/CU (1-wave WG slot cap) with the
// pixel front NOT allowed to widen (v5: wide front -> L2 thrash -> 1.4GB
// fetch).  Solution: same 8192 WGs x 64-px tiles (front unchanged), but each
// WG = 3 waves; wave wv handles candidates {3wv..3wv+2} on its own private
// LDS slabs with v4's two-phase coalesced gather + in-wave DS ordering (no
// barriers in the k-loop).  3x waves per WG slot -> ~15 waves/CU to overlap
// VMEM service.  One barrier at the end to merge the 3 online-softmax
// partials (exact merge: nm=max Mi; den=sum den_i*exp(Mi-nm); ...).
// ---------------------------------------------------------------------------
__global__ __launch_bounds__(192, 4) void eval_kernel_ks(const float* __restrict__ feat,
                                                         const float* __restrict__ offx,
                                                         const float* __restrict__ offy,
                                                         float* __restrict__ out) {
  __shared__ __align__(16) float scratch[3][32 * 36];  // per-wave gather scratch; reused for merge
  __shared__ __align__(16) float4 w_lds[3][64];        // per-wave bilinear weights
  __shared__ int a_lds[3][64];                         // per-wave row0-run float4 base index

  int tid = threadIdx.x;
  int wv = tid >> 6;  // wave 0..2 -> k-set {3wv, 3wv+1, 3wv+2}
  int ln = tid & 63;

  int blk = blockIdx.x;
  int region = blk & 7;  // XCD round-robin residue -> fixed 256x256 region
  int slot = blk >> 3;   // 0..1023 within region
  int b = region >> 2;
  int qd = region & 3;
  int qy = (qd >> 1) << 8;
  int qx = (qd & 1) << 8;
  int tr = slot >> 5;  // 0..31
  int tc = slot & 31;
  if (tr & 1) tc = 31 - tc;  // serpentine: consecutive blocks share halo
  int h = qy + tr * 8 + (ln >> 3);
  int w = qx + tc * 8 + (ln & 7);
  int ph = h * W_ + w;
  int p = b * HW_ + ph;

  const float4* feat4 = reinterpret_cast<const float4*>(feat);

  // this wave's 3 candidates' offsets for my pixel
  const float* oxb = offx + (size_t)b * K_ * HW_ + ph;
  const float* oyb = offy + (size_t)b * K_ * HW_ + ph;
  float oxv[3], oyv[3];
#pragma unroll
  for (int j = 0; j < 3; ++j) {
    oxv[j] = oxb[(3 * wv + j) * HW_];
    oyv[j] = oyb[(3 * wv + j) * HW_];
  }

  // own pixel's 36 center features -> registers
  float F[C_];
  {
    const float4* myF = feat4 + (size_t)p * 9;
#pragma unroll
    for (int i = 0; i < 9; ++i) {
      float4 v = myF[i];
      F[4 * i + 0] = v.x; F[4 * i + 1] = v.y; F[4 * i + 2] = v.z; F[4 * i + 3] = v.w;
    }
  }

  int g = ln / 9;      // gather group 0..7 (g==7 -> lane 63, stores suppressed)
  int q = ln - 9 * g;  // channel-quad within task

  float lx = (float)w;
  float ly = (float)h;

  float M = -INFINITY, den = 0.f, axs = 0.f, ays = 0.f;

  float* myScr = scratch[wv];

#pragma unroll 1
  for (int j = 0; j < 3; ++j) {
    // --- meta for my task (candidate k = 3*wv + j) ---
    float ox = oxv[j];
    float oy = oyv[j];
    float rx = fminf(fmaxf(lx + ox, 0.0f), 511.0f);
    float ry = fminf(fmaxf(ly + oy, 0.0f), 511.0f);
    float gx = (rx - 255.5f) / 255.5f;
    float gy = (ry - 255.5f) / 255.5f;
    float px = (gx + 1.0f) * 0.5f * 511.0f;
    float py = (gy + 1.0f) * 0.5f * 511.0f;
    int x0 = (int)floorf(px); x0 = (x0 > 510) ? 510 : x0;
    int y0 = (int)floorf(py); y0 = (y0 > 510) ? 510 : y0;
    float wx = px - (float)x0;
    float wy = py - (float)y0;
    w_lds[wv][ln] = make_float4((1.0f - wx) * (1.0f - wy), wx * (1.0f - wy),
                                (1.0f - wx) * wy, wx * wy);
    a_lds[wv][ln] = ((b * H_ + y0) * W_ + x0) * 9;  // float4 index of row0 run
    // no barrier: producer and consumers are the SAME wave; DS ops are
    // in-order per wave, and the compiler cannot reorder aliasing LDS ops.

    float4 L[5][4];
    // --- issue phase A (tasks 0..31): 20 coalesced 9-lane-run loads ---
#pragma unroll
    for (int r = 0; r < 5; ++r) {
      int tt = 7 * r + g;
      int t = (tt > 31) ? 31 : tt;
      const float4* r0 = feat4 + a_lds[wv][t];
      L[r][0] = r0[q];
      L[r][1] = r0[9 + q];
      L[r][2] = r0[ROWF4 + q];
      L[r][3] = r0[ROWF4 + 9 + q];
    }
    // --- consume phase A ---
#pragma unroll
    for (int r = 0; r < 5; ++r) {
      int tt = 7 * r + g;
      int t = (tt > 31) ? 31 : tt;
      float4 W4 = w_lds[wv][t];
      float4 v00 = L[r][0], v01 = L[r][1], v10 = L[r][2], v11 = L[r][3];
      float4 a4;
      a4.x = W4.x * v00.x + W4.y * v01.x + W4.z * v10.x + W4.w * v11.x;
      a4.y = W4.x * v00.y + W4.y * v01.y + W4.z * v10.y + W4.w * v11.y;
      a4.z = W4.x * v00.z + W4.y * v01.z + W4.z * v10.z + W4.w * v11.z;
      a4.w = W4.x * v00.w + W4.y * v01.w + W4.z * v10.w + W4.w * v11.w;
      if (tt < 32 && ln < 63) {
        *reinterpret_cast<float4*>(&myScr[t * 36 + 4 * q]) = a4;
      }
    }
    // --- issue phase B (tasks 32..63) BEFORE the phase-A reduce ---
#pragma unroll
    for (int r = 0; r < 5; ++r) {
      int tt = 32 + 7 * r + g;
      int t = (tt > 63) ? 63 : tt;
      const float4* r0 = feat4 + a_lds[wv][t];
      L[r][0] = r0[q];
      L[r][1] = r0[9 + q];
      L[r][2] = r0[ROWF4 + q];
      L[r][3] = r0[ROWF4 + 9 + q];
    }
    // --- phase-A owner reduce + softmax (lanes 0..31 own pixels 0..31) ---
    if (ln < 32) {
      float D[9] = {0.f, 0.f, 0.f, 0.f, 0.f, 0.f, 0.f, 0.f, 0.f};
      const float4* sc = reinterpret_cast<const float4*>(&myScr[ln * 36]);
#pragma unroll
      for (int q2 = 0; q2 < 9; ++q2) {
        float4 a4 = sc[q2];
        float av[4] = {a4.x, a4.y, a4.z, a4.w};
        int ga = q2 / 3;
        int f0 = 4 * (q2 % 3);
#pragma unroll
        for (int jj = 0; jj < 4; ++jj) {
          D[ga]     += fabsf(F[f0 + jj]      - av[jj]);
          D[3 + ga] += fabsf(F[12 + f0 + jj] - av[jj]);
          D[6 + ga] += fabsf(F[24 + f0 + jj] - av[jj]);
        }
      }
      float mn = D[0];
#pragma unroll
      for (int jj = 1; jj < 9; ++jj) mn = fminf(mn, D[jj]);
      float xk = -(mn / 12.0f) * 1000.0f;
      float nm = fmaxf(M, xk);
      float scl = expf(M - nm);
      float ek = expf(xk - nm);
      den = den * scl + ek;
      axs = axs * scl + ox * ek;
      ays = ays * scl + oy * ek;
      M = nm;
    }
    // --- consume phase B (in-order DS: these writes follow the reads above) ---
#pragma unroll
    for (int r = 0; r < 5; ++r) {
      int tt = 32 + 7 * r + g;
      int t = (tt > 63) ? 63 : tt;
      float4 W4 = w_lds[wv][t];
      float4 v00 = L[r][0], v01 = L[r][1], v10 = L[r][2], v11 = L[r][3];
      float4 a4;
      a4.x = W4.x * v00.x + W4.y * v01.x + W4.z * v10.x + W4.w * v11.x;
      a4.y = W4.x * v00.y + W4.y * v01.y + W4.z * v10.y + W4.w * v11.y;
      a4.z = W4.x * v00.z + W4.y * v01.z + W4.z * v10.z + W4.w * v11.z;
      a4.w = W4.x * v00.w + W4.y * v01.w + W4.z * v10.w + W4.w * v11.w;
      if (tt < 64 && ln < 63) {
        *reinterpret_cast<float4*>(&myScr[(t - 32) * 36 + 4 * q]) = a4;
      }
    }
    // --- phase-B owner reduce + softmax (lanes 32..63 own pixels 32..63) ---
    if (ln >= 32) {
      float D[9] = {0.f, 0.f, 0.f, 0.f, 0.f, 0.f, 0.f, 0.f, 0.f};
      const float4* sc = reinterpret_cast<const float4*>(&myScr[(ln - 32) * 36]);
#pragma unroll
      for (int q2 = 0; q2 < 9; ++q2) {
        float4 a4 = sc[q2];
        float av[4] = {a4.x, a4.y, a4.z, a4.w};
        int ga = q2 / 3;
        int f0 = 4 * (q2 % 3);
#pragma unroll
        for (int jj = 0; jj < 4; ++jj) {
          D[ga]     += fabsf(F[f0 + jj]      - av[jj]);
          D[3 + ga] += fabsf(F[12 + f0 + jj] - av[jj]);
          D[6 + ga] += fabsf(F[24 + f0 + jj] - av[jj]);
        }
      }
      float mn = D[0];
#pragma unroll
      for (int jj = 1; jj < 9; ++jj) mn = fminf(mn, D[jj]);
      float xk = -(mn / 12.0f) * 1000.0f;
      float nm = fmaxf(M, xk);
      float scl = expf(M - nm);
      float ek = expf(xk - nm);
      den = den * scl + ek;
      axs = axs * scl + ox * ek;
      ays = ays * scl + oy * ek;
      M = nm;
    }
  }

  // --- merge the 3 waves' partial softmax states (each lane owns pixel ln) ---
  *reinterpret_cast<float4*>(&myScr[ln * 4]) = make_float4(M, den, axs, ays);
  __syncthreads();
  if (wv == 0) {
    float4 s0 = *reinterpret_cast<const float4*>(&scratch[0][ln * 4]);
    float4 s1 = *reinterpret_cast<const float4*>(&scratch[1][ln * 4]);
    float4 s2 = *reinterpret_cast<const float4*>(&scratch[2][ln * 4]);
    float nm = fmaxf(s0.x, fmaxf(s1.x, s2.x));
    float e0 = expf(s0.x - nm);
    float e1 = expf(s1.x - nm);
    float e2 = expf(s2.x - nm);
    float dent = s0.y * e0 + s1.y * e1 + s2.y * e2;
    float ax = s0.z * e0 + s1.z * e1 + s2.z * e2;
    float ay = s0.w * e0 + s1.w * e1 + s2.w * e2;
    float resx = ax / dent;
    float resy = ay / dent;
    out[p] = fminf(fmaxf(resx + lx, 0.0f), 511.0f) - lx;
    out[B_ * HW_ + p] = fminf(fmaxf(resy + ly, 0.0f), 511.0f) - ly;
  }
}

// Fallback (no scratch): original channel-major layout, thread-per-pixel.
__global__ __launch_bounds__(256) void eval_kernel_n(const float* __restrict__ feat,
                                                     const float* __restrict__ offx,
                                                     const float* __restrict__ offy,
                                                     float* __restrict__ out) {
  int p = blockIdx.x * 256 + threadIdx.x;
  int ph = p & (HW_ - 1);
  int b = p >> 18;
  float F[C_];
  const float* fb = feat + (size_t)b * C_ * HW_ + ph;
#pragma unroll
  for (int c = 0; c < C_; ++c) F[c] = fb[(size_t)c * HW_];
  float lx = (float)(ph & (W_ - 1));
  float ly = (float)((ph >> 9) & (H_ - 1));
  const float* oxb = offx + (size_t)b * K_ * HW_ + ph;
  const float* oyb = offy + (size_t)b * K_ * HW_ + ph;
  float M = -INFINITY, den = 0.f, ax = 0.f, ay = 0.f;
#pragma unroll 1
  for (int k = 0; k < K_; ++k) {
    float ox = oxb[k * HW_];
    float oy = oyb[k * HW_];
    float rx = fminf(fmaxf(lx + ox, 0.0f), 511.0f);
    float ry = fminf(fmaxf(ly + oy, 0.0f), 511.0f);
    float gx = (rx - 255.5f) / 255.5f;
    float gy = (ry - 255.5f) / 255.5f;
    float px = (gx + 1.0f) * 0.5f * 511.0f;
    float py = (gy + 1.0f) * 0.5f * 511.0f;
    int x0 = (int)floorf(px); x0 = (x0 > 510) ? 510 : x0;
    int y0 = (int)floorf(py); y0 = (y0 > 510) ? 510 : y0;
    float wx = px - (float)x0;
    float wy = py - (float)y0;
    float w00 = (1.0f - wx) * (1.0f - wy);
    float w01 = wx * (1.0f - wy);
    float w10 = (1.0f - wx) * wy;
    float w11 = wx * wy;
    float D[9] = {0.f, 0.f, 0.f, 0.f, 0.f, 0.f, 0.f, 0.f, 0.f};
    const float* pl = feat + (size_t)b * C_ * HW_ + (size_t)y0 * W_ + x0;
#pragma unroll
    for (int c = 0; c < C_; ++c) {
      const float* q0 = pl + (size_t)c * HW_;
      float v00 = q0[0], v01 = q0[1];
      float v10 = q0[W_], v11 = q0[W_ + 1];
      float a = v00 * w00 + v01 * w01 + v10 * w10 + v11 * w11;
      int i = c % 12;
      int ga = c / 12;
      D[ga]     += fabsf(F[i]      - a);
      D[3 + ga] += fabsf(F[12 + i] - a);
      D[6 + ga] += fabsf(F[24 + i] - a);
    }
    float mn = D[0];
#pragma unroll
    for (int j = 1; j < 9; ++j) mn = fminf(mn, D[j]);
    float xk = -(mn / 12.0f) * 1000.0f;
    float nm = fmaxf(M, xk);
    float sc = expf(M - nm);
    float ek = expf(xk - nm);
    den = den * sc + ek;
    ax = ax * sc + ox * ek;
    ay = ay * sc + oy * ek;
    M = nm;
  }
  float resx = ax / den;
  float resy = ay / den;
  out[p] = fminf(fmaxf(resx + lx, 0.0f), 511.0f) - lx;
  out[B_ * HW_ + p] = fminf(fmaxf(resy + ly, 0.0f), 511.0f) - ly;
}

extern "C" void kernel_launch(void* const* d_in, const int* in_sizes, int n_in,
                              void* d_out, int out_size, void* d_ws, size_t ws_size,
                              hipStream_t stream) {
  const float* features = (const float*)d_in[0];
  const float* offset_x = (const float*)d_in[1];
  const float* offset_y = (const float*)d_in[2];
  float* out = (float*)d_out;

  const int npix = B_ * HW_;  // 524288
  const size_t need = (size_t)npix * C_ * sizeof(float);  // 75.5 MB

  if (ws_size >= need) {
    float* featT = (float*)d_ws;
    transpose_kernel2<<<B_ * H_ * 2, 256, 0, stream>>>(features, featT);
    eval_kernel_ks<<<npix / 64, 192, 0, stream>>>(featT, offset_x, offset_y, out);
  } else {
    eval_kernel_n<<<npix / 256, 256, 0, stream>>>(features, offset_x, offset_y, out);
  }
}

// Round 5
// 329.006 us; speedup vs baseline: 1.6604x; 1.6604x over previous
//
#include <hip/hip_runtime.h>
#include <math.h>

#define B_ 2
#define C_ 36
#define H_ 512
#define W_ 512
#define K_ 9
#define HW_ (H_ * W_)
#define ROWF4 (W_ * C_ / 4)  // float4 pitch of one image row in featT = 4608

// ---------------------------------------------------------------------------
// Transpose features [B,C,H,W] -> [B,H,W,C], v2.  (unchanged from round 3)
// ---------------------------------------------------------------------------
__global__ __launch_bounds__(256) void transpose_kernel2(const float* __restrict__ in,
                                                         float* __restrict__ out) {
  __shared__ float tile[256][37];  // 37.9 KB
  int blk = blockIdx.x;            // (b*H + h)*2 + strip
  int strip = blk & 1;
  int h = (blk >> 1) & (H_ - 1);
  int b = blk >> 10;
  int w0 = strip << 8;
  int tid = threadIdx.x;
  const float* src = in + (size_t)b * C_ * HW_ + (size_t)h * W_ + w0;
#pragma unroll
  for (int c = 0; c < C_; ++c) {
    tile[tid][c] = src[(size_t)c * HW_ + tid];
  }
  __syncthreads();
  float4* dst = reinterpret_cast<float4*>(out + (((size_t)b * H_ + h) * W_ + w0) * C_);
#pragma unroll
  for (int it = 0; it < 9; ++it) {
    int idx = it * 256 + tid;  // float4 index 0..2303
    int px = idx / 9;
    int qq = idx - 9 * px;
    dst[idx] = make_float4(tile[px][4 * qq + 0], tile[px][4 * qq + 1],
                           tile[px][4 * qq + 2], tile[px][4 * qq + 3]);
  }
}

// ---------------------------------------------------------------------------
// v8: v7's K-split (3 waves/WG, wave wv owns candidates {3wv..3wv+2}) with the
// register spill fixed.
// v7 post-mortem: __launch_bounds__(192,4) clamped VGPR to 64 (< ~130 live)
// -> ~600 MB of scratch spill/fill that missed L2 (spill set ~4.7 MB/XCD) ->
// 1.4 GB HBM traffic and 421 us.  Fix:
//   (1) __launch_bounds__(192,2): VGPR cap 256, allocator fits like v4 did.
//   (2) center features F[36] move from registers to F_lds[36][64]
//       (channel-major: reduce reads F_lds[c][ln] are bank-conflict-free,
//       init writes 2-way = free).  Removes 36 always-live VGPRs so the
//       kernel sits ~<=128 VGPR -> 4 waves/SIMD tier -> ~15 waves/CU to
//       overlap the ~38cyc/VMEM gather service (the measured wall).
// Geometry (8x8 serpentine tiles, 8192 WGs) unchanged: the pixel front per
// XCD stays a ~50-row band so featT gathers keep ~94% L2 hit (v5/v6 lesson).
// ---------------------------------------------------------------------------
__global__ __launch_bounds__(192, 2) void eval_kernel_ks(const float* __restrict__ feat,
                                                         const float* __restrict__ offx,
                                                         const float* __restrict__ offy,
                                                         float* __restrict__ out) {
  __shared__ __align__(16) float scratch[3][32 * 36];  // per-wave gather scratch; reused for merge
  __shared__ __align__(16) float4 w_lds[3][64];        // per-wave bilinear weights
  __shared__ int a_lds[3][64];                         // per-wave row0-run float4 base index
  __shared__ float F_lds[C_][64];                      // center features, channel-major (9.2 KB)

  int tid = threadIdx.x;
  int wv = tid >> 6;  // wave 0..2 -> k-set {3wv, 3wv+1, 3wv+2}
  int ln = tid & 63;

  int blk = blockIdx.x;
  int region = blk & 7;  // XCD round-robin residue -> fixed 256x256 region
  int slot = blk >> 3;   // 0..1023 within region
  int b = region >> 2;
  int qd = region & 3;
  int qy = (qd >> 1) << 8;
  int qx = (qd & 1) << 8;
  int tr = slot >> 5;  // 0..31
  int tc = slot & 31;
  if (tr & 1) tc = 31 - tc;  // serpentine: consecutive blocks share halo
  int h = qy + tr * 8 + (ln >> 3);
  int w = qx + tc * 8 + (ln & 7);
  int ph = h * W_ + w;
  int p = b * HW_ + ph;

  const float4* feat4 = reinterpret_cast<const float4*>(feat);

  // this wave's 3 candidates' offsets for my pixel
  const float* oxb = offx + (size_t)b * K_ * HW_ + ph;
  const float* oyb = offy + (size_t)b * K_ * HW_ + ph;
  float oxv[3], oyv[3];
#pragma unroll
  for (int j = 0; j < 3; ++j) {
    oxv[j] = oxb[(3 * wv + j) * HW_];
    oyv[j] = oyb[(3 * wv + j) * HW_];
  }

  // own pixel's center features -> LDS, cooperatively: wave wv loads channel
  // quads 3wv..3wv+2 of its pixel (disjoint (c,ln) cells, no races).
  {
    const float4* myF = feat4 + (size_t)p * 9;
#pragma unroll
    for (int i = 0; i < 3; ++i) {
      int ii = 3 * wv + i;
      float4 v = myF[ii];
      F_lds[4 * ii + 0][ln] = v.x;
      F_lds[4 * ii + 1][ln] = v.y;
      F_lds[4 * ii + 2][ln] = v.z;
      F_lds[4 * ii + 3][ln] = v.w;
    }
  }
  __syncthreads();

  int g = ln / 9;      // gather group 0..7 (g==7 -> lane 63, stores suppressed)
  int q = ln - 9 * g;  // channel-quad within task

  float lx = (float)w;
  float ly = (float)h;

  float M = -INFINITY, den = 0.f, axs = 0.f, ays = 0.f;

  float* myScr = scratch[wv];

#pragma unroll 1
  for (int j = 0; j < 3; ++j) {
    // --- meta for my task (candidate k = 3*wv + j) ---
    float ox = oxv[j];
    float oy = oyv[j];
    float rx = fminf(fmaxf(lx + ox, 0.0f), 511.0f);
    float ry = fminf(fmaxf(ly + oy, 0.0f), 511.0f);
    float gx = (rx - 255.5f) / 255.5f;
    float gy = (ry - 255.5f) / 255.5f;
    float px = (gx + 1.0f) * 0.5f * 511.0f;
    float py = (gy + 1.0f) * 0.5f * 511.0f;
    int x0 = (int)floorf(px); x0 = (x0 > 510) ? 510 : x0;
    int y0 = (int)floorf(py); y0 = (y0 > 510) ? 510 : y0;
    float wx = px - (float)x0;
    float wy = py - (float)y0;
    w_lds[wv][ln] = make_float4((1.0f - wx) * (1.0f - wy), wx * (1.0f - wy),
                                (1.0f - wx) * wy, wx * wy);
    a_lds[wv][ln] = ((b * H_ + y0) * W_ + x0) * 9;  // float4 index of row0 run
    // no barrier: producer and consumers are the SAME wave; DS ops are
    // in-order per wave.

    float4 L[5][4];
    // --- issue phase A (tasks 0..31): 20 coalesced 9-lane-run loads ---
#pragma unroll
    for (int r = 0; r < 5; ++r) {
      int tt = 7 * r + g;
      int t = (tt > 31) ? 31 : tt;
      const float4* r0 = feat4 + a_lds[wv][t];
      L[r][0] = r0[q];
      L[r][1] = r0[9 + q];
      L[r][2] = r0[ROWF4 + q];
      L[r][3] = r0[ROWF4 + 9 + q];
    }
    // --- consume phase A ---
#pragma unroll
    for (int r = 0; r < 5; ++r) {
      int tt = 7 * r + g;
      int t = (tt > 31) ? 31 : tt;
      float4 W4 = w_lds[wv][t];
      float4 v00 = L[r][0], v01 = L[r][1], v10 = L[r][2], v11 = L[r][3];
      float4 a4;
      a4.x = W4.x * v00.x + W4.y * v01.x + W4.z * v10.x + W4.w * v11.x;
      a4.y = W4.x * v00.y + W4.y * v01.y + W4.z * v10.y + W4.w * v11.y;
      a4.z = W4.x * v00.z + W4.y * v01.z + W4.z * v10.z + W4.w * v11.z;
      a4.w = W4.x * v00.w + W4.y * v01.w + W4.z * v10.w + W4.w * v11.w;
      if (tt < 32 && ln < 63) {
        *reinterpret_cast<float4*>(&myScr[t * 36 + 4 * q]) = a4;
      }
    }
    // --- issue phase B (tasks 32..63) BEFORE the phase-A reduce ---
#pragma unroll
    for (int r = 0; r < 5; ++r) {
      int tt = 32 + 7 * r + g;
      int t = (tt > 63) ? 63 : tt;
      const float4* r0 = feat4 + a_lds[wv][t];
      L[r][0] = r0[q];
      L[r][1] = r0[9 + q];
      L[r][2] = r0[ROWF4 + q];
      L[r][3] = r0[ROWF4 + 9 + q];
    }
    // --- phase-A owner reduce + softmax (lanes 0..31 own pixels 0..31) ---
    if (ln < 32) {
      float D[9] = {0.f, 0.f, 0.f, 0.f, 0.f, 0.f, 0.f, 0.f, 0.f};
      const float4* sc = reinterpret_cast<const float4*>(&myScr[ln * 36]);
#pragma unroll
      for (int q2 = 0; q2 < 9; ++q2) {
        float4 a4 = sc[q2];
        float av[4] = {a4.x, a4.y, a4.z, a4.w};
        int ga = q2 / 3;
        int f0 = 4 * (q2 % 3);
#pragma unroll
        for (int jj = 0; jj < 4; ++jj) {
          D[ga]     += fabsf(F_lds[f0 + jj][ln]      - av[jj]);
          D[3 + ga] += fabsf(F_lds[12 + f0 + jj][ln] - av[jj]);
          D[6 + ga] += fabsf(F_lds[24 + f0 + jj][ln] - av[jj]);
        }
      }
      float mn = D[0];
#pragma unroll
      for (int jj = 1; jj < 9; ++jj) mn = fminf(mn, D[jj]);
      float xk = -(mn / 12.0f) * 1000.0f;
      float nm = fmaxf(M, xk);
      float scl = expf(M - nm);
      float ek = expf(xk - nm);
      den = den * scl + ek;
      axs = axs * scl + ox * ek;
      ays = ays * scl + oy * ek;
      M = nm;
    }
    // --- consume phase B (in-order DS: these writes follow the reads above) ---
#pragma unroll
    for (int r = 0; r < 5; ++r) {
      int tt = 32 + 7 * r + g;
      int t = (tt > 63) ? 63 : tt;
      float4 W4 = w_lds[wv][t];
      float4 v00 = L[r][0], v01 = L[r][1], v10 = L[r][2], v11 = L[r][3];
      float4 a4;
      a4.x = W4.x * v00.x + W4.y * v01.x + W4.z * v10.x + W4.w * v11.x;
      a4.y = W4.x * v00.y + W4.y * v01.y + W4.z * v10.y + W4.w * v11.y;
      a4.z = W4.x * v00.z + W4.y * v01.z + W4.z * v10.z + W4.w * v11.z;
      a4.w = W4.x * v00.w + W4.y * v01.w + W4.z * v10.w + W4.w * v11.w;
      if (tt < 64 && ln < 63) {
        *reinterpret_cast<float4*>(&myScr[(t - 32) * 36 + 4 * q]) = a4;
      }
    }
    // --- phase-B owner reduce + softmax (lanes 32..63 own pixels 32..63) ---
    if (ln >= 32) {
      float D[9] = {0.f, 0.f, 0.f, 0.f, 0.f, 0.f, 0.f, 0.f, 0.f};
      const float4* sc = reinterpret_cast<const float4*>(&myScr[(ln - 32) * 36]);
#pragma unroll
      for (int q2 = 0; q2 < 9; ++q2) {
        float4 a4 = sc[q2];
        float av[4] = {a4.x, a4.y, a4.z, a4.w};
        int ga = q2 / 3;
        int f0 = 4 * (q2 % 3);
#pragma unroll
        for (int jj = 0; jj < 4; ++jj) {
          D[ga]     += fabsf(F_lds[f0 + jj][ln]      - av[jj]);
          D[3 + ga] += fabsf(F_lds[12 + f0 + jj][ln] - av[jj]);
          D[6 + ga] += fabsf(F_lds[24 + f0 + jj][ln] - av[jj]);
        }
      }
      float mn = D[0];
#pragma unroll
      for (int jj = 1; jj < 9; ++jj) mn = fminf(mn, D[jj]);
      float xk = -(mn / 12.0f) * 1000.0f;
      float nm = fmaxf(M, xk);
      float scl = expf(M - nm);
      float ek = expf(xk - nm);
      den = den * scl + ek;
      axs = axs * scl + ox * ek;
      ays = ays * scl + oy * ek;
      M = nm;
    }
  }

  // --- merge the 3 waves' partial softmax states (each lane owns pixel ln) ---
  *reinterpret_cast<float4*>(&myScr[ln * 4]) = make_float4(M, den, axs, ays);
  __syncthreads();
  if (wv == 0) {
    float4 s0 = *reinterpret_cast<const float4*>(&scratch[0][ln * 4]);
    float4 s1 = *reinterpret_cast<const float4*>(&scratch[1][ln * 4]);
    float4 s2 = *reinterpret_cast<const float4*>(&scratch[2][ln * 4]);
    float nm = fmaxf(s0.x, fmaxf(s1.x, s2.x));
    float e0 = expf(s0.x - nm);
    float e1 = expf(s1.x - nm);
    float e2 = expf(s2.x - nm);
    float dent = s0.y * e0 + s1.y * e1 + s2.y * e2;
    float ax = s0.z * e0 + s1.z * e1 + s2.z * e2;
    float ay = s0.w * e0 + s1.w * e1 + s2.w * e2;
    float resx = ax / dent;
    float resy = ay / dent;
    out[p] = fminf(fmaxf(resx + lx, 0.0f), 511.0f) - lx;
    out[B_ * HW_ + p] = fminf(fmaxf(resy + ly, 0.0f), 511.0f) - ly;
  }
}

// Fallback (no scratch): original channel-major layout, thread-per-pixel.
__global__ __launch_bounds__(256) void eval_kernel_n(const float* __restrict__ feat,
                                                     const float* __restrict__ offx,
                                                     const float* __restrict__ offy,
                                                     float* __restrict__ out) {
  int p = blockIdx.x * 256 + threadIdx.x;
  int ph = p & (HW_ - 1);
  int b = p >> 18;
  float F[C_];
  const float* fb = feat + (size_t)b * C_ * HW_ + ph;
#pragma unroll
  for (int c = 0; c < C_; ++c) F[c] = fb[(size_t)c * HW_];
  float lx = (float)(ph & (W_ - 1));
  float ly = (float)((ph >> 9) & (H_ - 1));
  const float* oxb = offx + (size_t)b * K_ * HW_ + ph;
  const float* oyb = offy + (size_t)b * K_ * HW_ + ph;
  float M = -INFINITY, den = 0.f, ax = 0.f, ay = 0.f;
#pragma unroll 1
  for (int k = 0; k < K_; ++k) {
    float ox = oxb[k * HW_];
    float oy = oyb[k * HW_];
    float rx = fminf(fmaxf(lx + ox, 0.0f), 511.0f);
    float ry = fminf(fmaxf(ly + oy, 0.0f), 511.0f);
    float gx = (rx - 255.5f) / 255.5f;
    float gy = (ry - 255.5f) / 255.5f;
    float px = (gx + 1.0f) * 0.5f * 511.0f;
    float py = (gy + 1.0f) * 0.5f * 511.0f;
    int x0 = (int)floorf(px); x0 = (x0 > 510) ? 510 : x0;
    int y0 = (int)floorf(py); y0 = (y0 > 510) ? 510 : y0;
    float wx = px - (float)x0;
    float wy = py - (float)y0;
    float w00 = (1.0f - wx) * (1.0f - wy);
    float w01 = wx * (1.0f - wy);
    float w10 = (1.0f - wx) * wy;
    float w11 = wx * wy;
    float D[9] = {0.f, 0.f, 0.f, 0.f, 0.f, 0.f, 0.f, 0.f, 0.f};
    const float* pl = feat + (size_t)b * C_ * HW_ + (size_t)y0 * W_ + x0;
#pragma unroll
    for (int c = 0; c < C_; ++c) {
      const float* q0 = pl + (size_t)c * HW_;
      float v00 = q0[0], v01 = q0[1];
      float v10 = q0[W_], v11 = q0[W_ + 1];
      float a = v00 * w00 + v01 * w01 + v10 * w10 + v11 * w11;
      int i = c % 12;
      int ga = c / 12;
      D[ga]     += fabsf(F[i]      - a);
      D[3 + ga] += fabsf(F[12 + i] - a);
      D[6 + ga] += fabsf(F[24 + i] - a);
    }
    float mn = D[0];
#pragma unroll
    for (int j = 1; j < 9; ++j) mn = fminf(mn, D[j]);
    float xk = -(mn / 12.0f) * 1000.0f;
    float nm = fmaxf(M, xk);
    float sc = expf(M - nm);
    float ek = expf(xk - nm);
    den = den * sc + ek;
    ax = ax * sc + ox * ek;
    ay = ay * sc + oy * ek;
    M = nm;
  }
  float resx = ax / den;
  float resy = ay / den;
  out[p] = fminf(fmaxf(resx + lx, 0.0f), 511.0f) - lx;
  out[B_ * HW_ + p] = fminf(fmaxf(resy + ly, 0.0f), 511.0f) - ly;
}

extern "C" void kernel_launch(void* const* d_in, const int* in_sizes, int n_in,
                              void* d_out, int out_size, void* d_ws, size_t ws_size,
                              hipStream_t stream) {
  const float* features = (const float*)d_in[0];
  const float* offset_x = (const float*)d_in[1];
  const float* offset_y = (const float*)d_in[2];
  float* out = (float*)d_out;

  const int npix = B_ * HW_;  // 524288
  const size_t need = (size_t)npix * C_ * sizeof(float);  // 75.5 MB

  if (ws_size >= need) {
    float* featT = (float*)d_ws;
    transpose_kernel2<<<B_ * H_ * 2, 256, 0, stream>>>(features, featT);
    eval_kernel_ks<<<npix / 64, 192, 0, stream>>>(featT, offset_x, offset_y, out);
  } else {
    eval_kernel_n<<<npix / 256, 256, 0, stream>>>(features, offset_x, offset_y, out);
  }
}